// Round 8
// baseline (290.432 us; speedup 1.0000x reference)
//
#include <hip/hip_runtime.h>
#include <hip/hip_bf16.h>
#include <stdint.h>

// N=4096, IN=512, OUT=64, H=8. Inputs (fp32): x, adj(int32), W, a1, a2. Output fp32[N, H*OUT].
// ws: bitsT 2MB @0 | WhhT 4MB @2M | f1 @6M | f2 @6M+128K | WTh 512K @6.5M | WTl 512K @7M

constexpr int N_ = 4096, IN_ = 512, OUT_ = 64, H_ = 8;
constexpr float ALPHA_ = 0.2f;

typedef __attribute__((ext_vector_type(8))) short short8;
typedef __attribute__((ext_vector_type(4))) float f32x4;

__device__ __forceinline__ uint32_t pkbf(float a, float b) {
    union { __hip_bfloat162 h2; uint32_t u; } c;
    c.h2 = __float22bfloat162_rn(make_float2(a, b));
    return c.u;
}
__device__ __forceinline__ uint32_t rne_pack2(float a, float b, float& ra, float& rb) {
    uint32_t ua = __float_as_uint(a); ua += 0x7fffu + ((ua >> 16) & 1u); ua >>= 16;
    uint32_t ub = __float_as_uint(b); ub += 0x7fffu + ((ub >> 16) & 1u); ub >>= 16;
    ra = __uint_as_float(ua << 16);
    rb = __uint_as_float(ub << 16);
    return ua | (ub << 16);
}
__device__ __forceinline__ short8 ld_bf8(const uint16_t* ptr) {
    union { uint4 v; short8 s; } u;
    u.v = *(const uint4*)ptr;
    return u.s;
}

// ---------- pack adj -> transposed bitmask bitsT[c*N + n], bit i = adj[n][c*64+i]
__global__ __launch_bounds__(256) void pack_adj(const int* __restrict__ adj,
                                                unsigned long long* __restrict__ bitsT) {
    size_t g = (size_t)blockIdx.x * 256 + threadIdx.x;   // g = n*4096 + m
    int v = adj[g];
    unsigned long long m = __ballot(v != 0);
    if ((threadIdx.x & 63) == 0) {
        int n = (int)(g >> 12);
        int c = (int)((g >> 6) & 63);
        bitsT[(size_t)c * N_ + n] = m;
    }
}

// ---------- W [h][k][o] fp32 -> WT hi/lo bf16 [h][o][k] (B-operand layout)
__global__ __launch_bounds__(256) void split_wT(const float* __restrict__ W,
                                                uint16_t* __restrict__ WTh,
                                                uint16_t* __restrict__ WTl) {
    __shared__ float T[64 * 68];
    const int t  = threadIdx.x;
    const int kb = blockIdx.x;   // 0..7
    const int h  = blockIdx.y;
    {
        int kk = t >> 2, os = (t & 3) * 16;
        const float* src = W + ((size_t)h * IN_ + kb * 64 + kk) * OUT_ + os;
#pragma unroll
        for (int j = 0; j < 4; j++)
            *(float4*)&T[kk * 68 + os + j * 4] = *(const float4*)(src + j * 4);
    }
    __syncthreads();
    int o = t >> 2, ks = (t & 3) * 16;
    uint32_t ph[8], pl[8];
#pragma unroll
    for (int i = 0; i < 8; i++) {
        float va = T[(ks + 2 * i) * 68 + o], vb = T[(ks + 2 * i + 1) * 68 + o];
        float h0, h1, d0, d1;
        ph[i] = rne_pack2(va, vb, h0, h1);
        pl[i] = rne_pack2(va - h0, vb - h1, d0, d1);
    }
    size_t dst = ((size_t)h * OUT_ + o) * IN_ + kb * 64 + ks;
    *(uint4*)&WTh[dst]     = make_uint4(ph[0], ph[1], ph[2], ph[3]);
    *(uint4*)&WTh[dst + 8] = make_uint4(ph[4], ph[5], ph[6], ph[7]);
    *(uint4*)&WTl[dst]     = make_uint4(pl[0], pl[1], pl[2], pl[3]);
    *(uint4*)&WTl[dst + 8] = make_uint4(pl[4], pl[5], pl[6], pl[7]);
}

// ---------- Wh = x@W via MFMA, barrier-free K-loop (direct global fragments).
// Each wave owns 16 n-rows, all 64 o-cols. Epilogue (LDS): f1/f2 + WhhT bf16 [h][o][n].
__global__ __launch_bounds__(256) void wh_mfma(const float* __restrict__ x,
                                               const uint16_t* __restrict__ WTh,
                                               const uint16_t* __restrict__ WTl,
                                               const float* __restrict__ a1,
                                               const float* __restrict__ a2,
                                               uint16_t* __restrict__ WhhT,
                                               float* __restrict__ f1,
                                               float* __restrict__ f2) {
    __shared__ __align__(16) float Whs[64 * 68];
    const int t = threadIdx.x, h = blockIdx.y, n0 = blockIdx.x * 64;
    const int l = t & 63, w = t >> 6, p = l & 15, q = l >> 4;

    f32x4 acc[4];
#pragma unroll
    for (int ct = 0; ct < 4; ct++) acc[ct] = (f32x4){0.f, 0.f, 0.f, 0.f};

    const float* gx = x + (size_t)(n0 + w * 16 + p) * IN_ + q * 8;
    const uint16_t* gbh[4];
    const uint16_t* gbl[4];
#pragma unroll
    for (int ct = 0; ct < 4; ct++) {
        gbh[ct] = WTh + ((size_t)h * OUT_ + ct * 16 + p) * IN_ + q * 8;
        gbl[ct] = WTl + ((size_t)h * OUT_ + ct * 16 + p) * IN_ + q * 8;
    }

    for (int kt = 0; kt < 8; kt++) {
#pragma unroll
        for (int k0 = 0; k0 < 2; k0++) {
            const int off = kt * 64 + k0 * 32;
            float4 xa = *(const float4*)(gx + off);
            float4 xb = *(const float4*)(gx + off + 4);
            float va[8] = {xa.x, xa.y, xa.z, xa.w, xb.x, xb.y, xb.z, xb.w};
            union { short8 s; uint32_t u[4]; } ah, al;
#pragma unroll
            for (int i = 0; i < 4; i++) {
                ah.u[i] = pkbf(va[2 * i], va[2 * i + 1]);
                float ha = __uint_as_float(ah.u[i] << 16);
                float hb = __uint_as_float(ah.u[i] & 0xffff0000u);
                al.u[i] = pkbf(va[2 * i] - ha, va[2 * i + 1] - hb);
            }
#pragma unroll
            for (int ct = 0; ct < 4; ct++) {
                short8 bh = ld_bf8(gbh[ct] + off);
                short8 bl = ld_bf8(gbl[ct] + off);
                acc[ct] = __builtin_amdgcn_mfma_f32_16x16x32_bf16(ah.s, bh, acc[ct], 0, 0, 0);
                acc[ct] = __builtin_amdgcn_mfma_f32_16x16x32_bf16(al.s, bh, acc[ct], 0, 0, 0);
                acc[ct] = __builtin_amdgcn_mfma_f32_16x16x32_bf16(ah.s, bl, acc[ct], 0, 0, 0);
            }
        }
    }
    // epilogue: acc -> LDS (rows n, cols o), then f1/f2 + WhhT
#pragma unroll
    for (int ct = 0; ct < 4; ct++)
#pragma unroll
        for (int reg = 0; reg < 4; reg++)
            Whs[(w * 16 + q * 4 + reg) * 68 + ct * 16 + p] = acc[ct][reg];
    __syncthreads();
    {   // f1/f2: thread group of 4 covers one row
        int r = t >> 2, og = (t & 3) * 16;
        float s1 = 0.f, s2 = 0.f;
#pragma unroll
        for (int j = 0; j < 4; j++) {
            float4 wv = *(const float4*)&Whs[r * 68 + og + j * 4];
            float4 av = *(const float4*)(a1 + h * OUT_ + og + j * 4);
            float4 bv = *(const float4*)(a2 + h * OUT_ + og + j * 4);
            s1 += wv.x * av.x + wv.y * av.y + wv.z * av.z + wv.w * av.w;
            s2 += wv.x * bv.x + wv.y * bv.y + wv.z * bv.z + wv.w * bv.w;
        }
        s1 += __shfl_xor(s1, 1, 64); s1 += __shfl_xor(s1, 2, 64);
        s2 += __shfl_xor(s2, 1, 64); s2 += __shfl_xor(s2, 2, 64);
        if ((t & 3) == 0) {
            f1[(size_t)h * N_ + n0 + r] = s1;
            f2[(size_t)h * N_ + n0 + r] = s2;
        }
    }
    {   // WhhT bf16 (hi only), [h][o][n]
        int o = t >> 2, ns = (t & 3) * 16;
        uint32_t ph[8];
#pragma unroll
        for (int i = 0; i < 8; i++) {
            float va = Whs[(ns + 2 * i) * 68 + o], vb = Whs[(ns + 2 * i + 1) * 68 + o];
            float h0, h1;
            ph[i] = rne_pack2(va, vb, h0, h1);
        }
        size_t dst = ((size_t)h * OUT_ + o) * N_ + n0 + ns;
        *(uint4*)&WhhT[dst]     = make_uint4(ph[0], ph[1], ph[2], ph[3]);
        *(uint4*)&WhhT[dst + 8] = make_uint4(ph[4], ph[5], ph[6], ph[7]);
    }
}

// ---------- main: barrier-free, LDS-free. P in-register (A-layout), B direct from global,
// L via ones-MFMA (exactly consistent with rounded P), normalization fused.
__global__ __launch_bounds__(256) void gat_main(const unsigned long long* __restrict__ bitsT,
                                                const uint16_t* __restrict__ WhhT,
                                                const float* __restrict__ f1,
                                                const float* __restrict__ f2,
                                                float* __restrict__ out) {
    const int t = threadIdx.x, h = blockIdx.y, n0 = blockIdx.x * 64;
    const int l = t & 63, w = t >> 6, p = l & 15, q = l >> 4;
    const int row = w * 16 + p;                      // this lane's P row (A-frag m)

    const float f1v = f1[(size_t)h * N_ + n0 + row];
    const float* f2b = f2 + (size_t)h * N_ + q * 8;
    const unsigned long long* bp = bitsT + n0 + row;
    const uint16_t* gb[4];
#pragma unroll
    for (int ct = 0; ct < 4; ct++)
        gb[ct] = WhhT + ((size_t)h * OUT_ + ct * 16 + p) * N_ + q * 8;

    short8 ones;
    {
        union { short8 s; uint32_t u[4]; } o;
        o.u[0] = o.u[1] = o.u[2] = o.u[3] = 0x3f803f80u;   // bf16 1.0 pair
        ones = o.s;
    }

    f32x4 acc[4], accL;
#pragma unroll
    for (int ct = 0; ct < 4; ct++) acc[ct] = (f32x4){0.f, 0.f, 0.f, 0.f};
    accL = (f32x4){0.f, 0.f, 0.f, 0.f};

    for (int chunk = 0; chunk < 64; chunk++) {
        const int m0 = chunk * 64;
        unsigned long long word = bp[(size_t)chunk * N_];
#pragma unroll
        for (int k0 = 0; k0 < 2; k0++) {
            const int off = m0 + k0 * 32;
            short8 b0 = ld_bf8(gb[0] + off);
            short8 b1 = ld_bf8(gb[1] + off);
            short8 b2 = ld_bf8(gb[2] + off);
            short8 b3 = ld_bf8(gb[3] + off);
            float4 fv0 = *(const float4*)(f2b + off);
            float4 fv1 = *(const float4*)(f2b + off + 4);
            float fs[8] = {fv0.x, fv0.y, fv0.z, fv0.w, fv1.x, fv1.y, fv1.z, fv1.w};
            uint32_t bits8 = (uint32_t)(word >> (k0 * 32 + q * 8)) & 0xffu;
            union { short8 s; uint32_t u[4]; } af;
#pragma unroll
            for (int i = 0; i < 4; i++) {
                float s0 = f1v + fs[2 * i];
                float s1 = f1v + fs[2 * i + 1];
                float e0 = fmaxf(s0, ALPHA_ * s0);
                float e1 = fmaxf(s1, ALPHA_ * s1);
                float x0 = ((bits8 >> (2 * i)) & 1u) ? __expf(e0) : 0.f;
                float x1 = ((bits8 >> (2 * i + 1)) & 1u) ? __expf(e1) : 0.f;
                af.u[i] = pkbf(x0, x1);
            }
            accL   = __builtin_amdgcn_mfma_f32_16x16x32_bf16(af.s, ones, accL, 0, 0, 0);
            acc[0] = __builtin_amdgcn_mfma_f32_16x16x32_bf16(af.s, b0, acc[0], 0, 0, 0);
            acc[1] = __builtin_amdgcn_mfma_f32_16x16x32_bf16(af.s, b1, acc[1], 0, 0, 0);
            acc[2] = __builtin_amdgcn_mfma_f32_16x16x32_bf16(af.s, b2, acc[2], 0, 0, 0);
            acc[3] = __builtin_amdgcn_mfma_f32_16x16x32_bf16(af.s, b3, acc[3], 0, 0, 0);
        }
    }
    // epilogue: C/D layout col=lane&15, row=(lane>>4)*4+reg; accL row matches.
    float invL[4];
#pragma unroll
    for (int reg = 0; reg < 4; reg++) invL[reg] = 1.0f / accL[reg];
#pragma unroll
    for (int ct = 0; ct < 4; ct++)
#pragma unroll
        for (int reg = 0; reg < 4; reg++) {
            int rr = w * 16 + q * 4 + reg;
            out[(size_t)(n0 + rr) * (H_ * OUT_) + h * OUT_ + ct * 16 + p] = acc[ct][reg] * invL[reg];
        }
}

extern "C" void kernel_launch(void* const* d_in, const int* in_sizes, int n_in,
                              void* d_out, int out_size, void* d_ws, size_t ws_size,
                              hipStream_t stream) {
    const float* x   = nullptr;
    const int*   adj = nullptr;
    const float* W   = nullptr;
    const float* a1  = nullptr;
    const float* a2  = nullptr;
    for (int i = 0; i < n_in; i++) {
        long long sz = in_sizes[i];
        if      (sz == (long long)N_ * IN_)        x   = (const float*)d_in[i];
        else if (sz == (long long)N_ * N_)         adj = (const int*)d_in[i];
        else if (sz == (long long)H_ * IN_ * OUT_) W   = (const float*)d_in[i];
        else if (sz == (long long)H_ * OUT_) {
            if (!a1) a1 = (const float*)d_in[i];
            else     a2 = (const float*)d_in[i];
        }
    }
    if (!x)   x   = (const float*)d_in[0];
    if (!adj) adj = (const int*)d_in[1];
    if (!W)   W   = (const float*)d_in[2];
    if (!a1)  a1  = (const float*)d_in[3];
    if (!a2)  a2  = (const float*)d_in[4];
    float* out = (float*)d_out;

    char* ws = (char*)d_ws;
    unsigned long long* bitsT = (unsigned long long*)ws;                     // 2 MB @0
    uint16_t* WhhT = (uint16_t*)(ws + (2u << 20));                           // 4 MB @2M
    float* f1      = (float*)   (ws + (6u << 20));                           // 128 KB
    float* f2      = (float*)   (ws + (6u << 20) + (128u << 10));            // 128 KB
    uint16_t* WTh  = (uint16_t*)(ws + (6u << 20) + (512u << 10));            // 512 KB
    uint16_t* WTl  = (uint16_t*)(ws + (7u << 20));                           // 512 KB

    pack_adj<<<(N_ * (size_t)N_) / 256, 256, 0, stream>>>(adj, bitsT);
    split_wT<<<dim3(IN_ / 64, H_), 256, 0, stream>>>(W, WTh, WTl);
    wh_mfma<<<dim3(N_ / 64, H_), 256, 0, stream>>>(x, WTh, WTl, a1, a2, WhhT, f1, f2);
    gat_main<<<dim3(N_ / 64, H_), 256, 0, stream>>>(bitsT, WhhT, f1, f2, out);
}

// Round 9
// 239.075 us; speedup vs baseline: 1.2148x; 1.2148x over previous
//
#include <hip/hip_runtime.h>
#include <hip/hip_bf16.h>
#include <stdint.h>

// N=4096, IN=512, OUT=64, H=8. Inputs (fp32): x, adj(int32), W, a1, a2. Output fp32[N, H*OUT].
// ws: bitsT 2MB @0 | WhhT 4MB @2M | f1 @6M | f2 @6M+128K | WTh @6.5M | WTl @7M |
//     EF1 @7.5M | EF2 @7.75M | Lpart @8M | op1 8MB @8.25M   => 16.25 MB

constexpr int N_ = 4096, IN_ = 512, OUT_ = 64, H_ = 8;
constexpr float ALPHA_ = 0.2f;

typedef __attribute__((ext_vector_type(8))) short short8;
typedef __attribute__((ext_vector_type(4))) float f32x4;

__device__ __forceinline__ uint32_t pkbf(float a, float b) {
    union { __hip_bfloat162 h2; uint32_t u; } c;
    c.h2 = __float22bfloat162_rn(make_float2(a, b));
    return c.u;
}
__device__ __forceinline__ uint32_t rne_pack2(float a, float b, float& ra, float& rb) {
    uint32_t ua = __float_as_uint(a); ua += 0x7fffu + ((ua >> 16) & 1u); ua >>= 16;
    uint32_t ub = __float_as_uint(b); ub += 0x7fffu + ((ub >> 16) & 1u); ub >>= 16;
    ra = __uint_as_float(ua << 16);
    rb = __uint_as_float(ub << 16);
    return ua | (ub << 16);
}
__device__ __forceinline__ short8 ld_bf8(const uint16_t* ptr) {
    union { uint4 v; short8 s; } u;
    u.v = *(const uint4*)ptr;
    return u.s;
}

// ---------- pack adj -> transposed bitmask bitsT[c*N + n], bit i = adj[n][c*64+i]
__global__ __launch_bounds__(256) void pack_adj(const int* __restrict__ adj,
                                                unsigned long long* __restrict__ bitsT) {
    size_t g = (size_t)blockIdx.x * 256 + threadIdx.x;   // g = n*4096 + m
    int v = adj[g];
    unsigned long long m = __ballot(v != 0);
    if ((threadIdx.x & 63) == 0) {
        int n = (int)(g >> 12);
        int c = (int)((g >> 6) & 63);
        bitsT[(size_t)c * N_ + n] = m;
    }
}

// ---------- W [h][k][o] fp32 -> WT hi/lo bf16 [h][o][k] (B-operand layout)
__global__ __launch_bounds__(256) void split_wT(const float* __restrict__ W,
                                                uint16_t* __restrict__ WTh,
                                                uint16_t* __restrict__ WTl) {
    __shared__ float T[64 * 68];
    const int t  = threadIdx.x;
    const int kb = blockIdx.x;   // 0..7
    const int h  = blockIdx.y;
    {
        int kk = t >> 2, os = (t & 3) * 16;
        const float* src = W + ((size_t)h * IN_ + kb * 64 + kk) * OUT_ + os;
#pragma unroll
        for (int j = 0; j < 4; j++)
            *(float4*)&T[kk * 68 + os + j * 4] = *(const float4*)(src + j * 4);
    }
    __syncthreads();
    int o = t >> 2, ks = (t & 3) * 16;
    uint32_t ph[8], pl[8];
#pragma unroll
    for (int i = 0; i < 8; i++) {
        float va = T[(ks + 2 * i) * 68 + o], vb = T[(ks + 2 * i + 1) * 68 + o];
        float h0, h1, d0, d1;
        ph[i] = rne_pack2(va, vb, h0, h1);
        pl[i] = rne_pack2(va - h0, vb - h1, d0, d1);
    }
    size_t dst = ((size_t)h * OUT_ + o) * IN_ + kb * 64 + ks;
    *(uint4*)&WTh[dst]     = make_uint4(ph[0], ph[1], ph[2], ph[3]);
    *(uint4*)&WTh[dst + 8] = make_uint4(ph[4], ph[5], ph[6], ph[7]);
    *(uint4*)&WTl[dst]     = make_uint4(pl[0], pl[1], pl[2], pl[3]);
    *(uint4*)&WTl[dst + 8] = make_uint4(pl[4], pl[5], pl[6], pl[7]);
}

// ---------- Wh GEMM, col-split for occupancy: grid (64,8,4), block = 64 rows x 16 cols.
// Wave w: rows w*16..+16, cols ct*16..+16. Hi/lo 3-MFMA product (fp32-accurate).
// Epilogue: WhhT bf16 [h][o][n] + f1/f2 partial dots via atomicAdd.
__global__ __launch_bounds__(256) void wh_col(const float* __restrict__ x,
                                              const uint16_t* __restrict__ WTh,
                                              const uint16_t* __restrict__ WTl,
                                              const float* __restrict__ a1,
                                              const float* __restrict__ a2,
                                              uint16_t* __restrict__ WhhT,
                                              float* __restrict__ f1,
                                              float* __restrict__ f2) {
    __shared__ float Ws[64 * 17];
    const int t = threadIdx.x, h = blockIdx.y, ct = blockIdx.z, n0 = blockIdx.x * 64;
    const int l = t & 63, w = t >> 6, p = l & 15, q = l >> 4;

    f32x4 acc = (f32x4){0.f, 0.f, 0.f, 0.f};
    const float* gx = x + (size_t)(n0 + w * 16 + p) * IN_ + q * 8;
    const uint16_t* gbh = WTh + ((size_t)h * OUT_ + ct * 16 + p) * IN_ + q * 8;
    const uint16_t* gbl = WTl + ((size_t)h * OUT_ + ct * 16 + p) * IN_ + q * 8;

#pragma unroll 4
    for (int ks = 0; ks < 16; ks++) {
        const int off = ks * 32;
        float4 xa = *(const float4*)(gx + off);
        float4 xb = *(const float4*)(gx + off + 4);
        float va[8] = {xa.x, xa.y, xa.z, xa.w, xb.x, xb.y, xb.z, xb.w};
        union { short8 s; uint32_t u[4]; } ah, al;
#pragma unroll
        for (int i = 0; i < 4; i++) {
            ah.u[i] = pkbf(va[2 * i], va[2 * i + 1]);
            float ha = __uint_as_float(ah.u[i] << 16);
            float hb = __uint_as_float(ah.u[i] & 0xffff0000u);
            al.u[i] = pkbf(va[2 * i] - ha, va[2 * i + 1] - hb);
        }
        short8 bh = ld_bf8(gbh + off);
        short8 bl = ld_bf8(gbl + off);
        acc = __builtin_amdgcn_mfma_f32_16x16x32_bf16(ah.s, bh, acc, 0, 0, 0);
        acc = __builtin_amdgcn_mfma_f32_16x16x32_bf16(al.s, bh, acc, 0, 0, 0);
        acc = __builtin_amdgcn_mfma_f32_16x16x32_bf16(ah.s, bl, acc, 0, 0, 0);
    }
    // C/D: col = p, row = q*4+reg (within wave's 16 rows)
#pragma unroll
    for (int reg = 0; reg < 4; reg++)
        Ws[(w * 16 + q * 4 + reg) * 17 + p] = acc[reg];
    __syncthreads();
    if (t < 64) {   // f1/f2 partial dot over this block's 16 cols
        float s1 = 0.f, s2 = 0.f;
#pragma unroll
        for (int j = 0; j < 16; j++) {
            float wv = Ws[t * 17 + j];
            s1 += wv * a1[h * OUT_ + ct * 16 + j];
            s2 += wv * a2[h * OUT_ + ct * 16 + j];
        }
        atomicAdd(&f1[(size_t)h * N_ + n0 + t], s1);
        atomicAdd(&f2[(size_t)h * N_ + n0 + t], s2);
    }
    {   // WhhT bf16 [h][o][n]
        int o = t >> 4, ns = (t & 15) * 4;
        float v0 = Ws[(ns + 0) * 17 + o], v1 = Ws[(ns + 1) * 17 + o];
        float v2 = Ws[(ns + 2) * 17 + o], v3 = Ws[(ns + 3) * 17 + o];
        uint2 st = make_uint2(pkbf(v0, v1), pkbf(v2, v3));
        *(uint2*)&WhhT[((size_t)h * OUT_ + ct * 16 + o) * N_ + n0 + ns] = st;
    }
}

// ---------- EF vectors: EF1[h,n] = (exp(f1), exp(0.2 f1)), EF2 likewise from f2
__global__ __launch_bounds__(256) void prep_ef(const float* __restrict__ f1,
                                               const float* __restrict__ f2,
                                               float2* __restrict__ EF1,
                                               float2* __restrict__ EF2) {
    size_t g = (size_t)blockIdx.x * 256 + threadIdx.x;
    float v1 = f1[g], v2 = f2[g];
    EF1[g] = make_float2(__expf(v1), __expf(ALPHA_ * v1));
    EF2[g] = make_float2(__expf(v2), __expf(ALPHA_ * v2));
}

// ---------- main: LDS-staged B (R7 skeleton), factored exp (max of products),
// pkbf pack, L via ones-MFMA. grid (64, 8, 2): raw numerators + L partials.
__global__ __launch_bounds__(256) void gat_main(const unsigned long long* __restrict__ bitsT,
                                                const uint16_t* __restrict__ WhhT,
                                                const float2* __restrict__ EF1,
                                                const float2* __restrict__ EF2,
                                                float* __restrict__ outNum,
                                                float* __restrict__ op1,
                                                float* __restrict__ Lpart) {
    __shared__ __align__(16) uint16_t Bh[64 * 72];   // 9216 B
    const int t = threadIdx.x, h = blockIdx.y, z = blockIdx.z, n0 = blockIdx.x * 64;
    const int l = t & 63, w = t >> 6, p = l & 15, q = l >> 4;
    const int sr = t >> 2, sc = (t & 3) * 16;
    const int row = w * 16 + p;                      // this lane's P row (A-frag m)

    const float2 ef1 = EF1[(size_t)h * N_ + n0 + row];
    const float E1v = ef1.x, F1v = ef1.y;
    const float2* efb = EF2 + (size_t)h * N_ + q * 8;
    const unsigned long long* bp = bitsT + n0 + row;
    const uint16_t* gb = WhhT + ((size_t)h * OUT_ + sr) * N_ + sc;

    short8 ones;
    {
        union { short8 s; uint32_t u[4]; } o;
        o.u[0] = o.u[1] = o.u[2] = o.u[3] = 0x3f803f80u;   // bf16 1.0 pair
        ones = o.s;
    }

    f32x4 acc[4], accL;
#pragma unroll
    for (int ct = 0; ct < 4; ct++) acc[ct] = (f32x4){0.f, 0.f, 0.f, 0.f};
    accL = (f32x4){0.f, 0.f, 0.f, 0.f};

    for (int cc = 0; cc < 32; cc++) {
        const int chunk = z * 32 + cc;
        const int m0 = chunk * 64;
        __syncthreads();   // prev MFMA reads done with Bh
        uint4 b0 = *(const uint4*)(gb + m0);
        uint4 b1 = *(const uint4*)(gb + m0 + 8);
        *(uint4*)&Bh[sr * 72 + sc]     = b0;
        *(uint4*)&Bh[sr * 72 + sc + 8] = b1;
        unsigned long long word = bp[(size_t)chunk * N_];
        // P fragments for both k0-halves, in-register (hides staging latency)
        union { short8 s; uint32_t u[4]; } af[2];
#pragma unroll
        for (int k0 = 0; k0 < 2; k0++) {
            const float4* ep = (const float4*)(efb + m0 + k0 * 32);
            float4 e0 = ep[0], e1 = ep[1], e2 = ep[2], e3 = ep[3];
            float ev[8] = {e0.x, e0.z, e1.x, e1.z, e2.x, e2.z, e3.x, e3.z};   // E2
            float fv[8] = {e0.y, e0.w, e1.y, e1.w, e2.y, e2.w, e3.y, e3.w};   // F2
            uint32_t bits8 = (uint32_t)(word >> (k0 * 32 + q * 8)) & 0xffu;
            float pv[8];
#pragma unroll
            for (int j = 0; j < 8; j++) {
                float m = fmaxf(E1v * ev[j], F1v * fv[j]);   // = exp(leakyrelu(f1+f2))
                pv[j] = ((bits8 >> j) & 1u) ? m : 0.f;
            }
#pragma unroll
            for (int i = 0; i < 4; i++) af[k0].u[i] = pkbf(pv[2 * i], pv[2 * i + 1]);
        }
        __syncthreads();   // Bh visible
#pragma unroll
        for (int k0 = 0; k0 < 2; k0++) {
            short8 bb0 = ld_bf8(&Bh[(0 * 16 + p) * 72 + q * 8 + k0 * 32]);
            short8 bb1 = ld_bf8(&Bh[(1 * 16 + p) * 72 + q * 8 + k0 * 32]);
            short8 bb2 = ld_bf8(&Bh[(2 * 16 + p) * 72 + q * 8 + k0 * 32]);
            short8 bb3 = ld_bf8(&Bh[(3 * 16 + p) * 72 + q * 8 + k0 * 32]);
            accL   = __builtin_amdgcn_mfma_f32_16x16x32_bf16(af[k0].s, ones, accL, 0, 0, 0);
            acc[0] = __builtin_amdgcn_mfma_f32_16x16x32_bf16(af[k0].s, bb0, acc[0], 0, 0, 0);
            acc[1] = __builtin_amdgcn_mfma_f32_16x16x32_bf16(af[k0].s, bb1, acc[1], 0, 0, 0);
            acc[2] = __builtin_amdgcn_mfma_f32_16x16x32_bf16(af[k0].s, bb2, acc[2], 0, 0, 0);
            acc[3] = __builtin_amdgcn_mfma_f32_16x16x32_bf16(af[k0].s, bb3, acc[3], 0, 0, 0);
        }
    }
    // L: accL columns are identical (B=ones); row = w*16 + q*4 + reg
    if (p == 0) {
#pragma unroll
        for (int reg = 0; reg < 4; reg++)
            Lpart[((size_t)z * 8 + h) * N_ + n0 + w * 16 + q * 4 + reg] = accL[reg];
    }
    float* dst = (z == 0) ? outNum : op1;
#pragma unroll
    for (int ct = 0; ct < 4; ct++)
#pragma unroll
        for (int reg = 0; reg < 4; reg++) {
            int rr = w * 16 + q * 4 + reg;
            dst[(size_t)(n0 + rr) * (H_ * OUT_) + h * OUT_ + ct * 16 + p] = acc[ct][reg];
        }
}

// ---------- combine halves + normalize
__global__ __launch_bounds__(256) void combine(float* __restrict__ outb,
                                               const float* __restrict__ op1,
                                               const float* __restrict__ Lpart) {
    size_t g = (size_t)blockIdx.x * 256 + threadIdx.x;   // float4 index
    int n = (int)(g >> 7);
    int c = (int)(g & 127);
    int h = c >> 4;
    float4 o0 = ((const float4*)outb)[g];
    float4 o1 = ((const float4*)op1)[g];
    float L = Lpart[(size_t)h * N_ + n] + Lpart[(size_t)(8 + h) * N_ + n];
    float inv = 1.f / L;
    ((float4*)outb)[g] = make_float4((o0.x + o1.x) * inv, (o0.y + o1.y) * inv,
                                     (o0.z + o1.z) * inv, (o0.w + o1.w) * inv);
}

extern "C" void kernel_launch(void* const* d_in, const int* in_sizes, int n_in,
                              void* d_out, int out_size, void* d_ws, size_t ws_size,
                              hipStream_t stream) {
    const float* x   = nullptr;
    const int*   adj = nullptr;
    const float* W   = nullptr;
    const float* a1  = nullptr;
    const float* a2  = nullptr;
    for (int i = 0; i < n_in; i++) {
        long long sz = in_sizes[i];
        if      (sz == (long long)N_ * IN_)        x   = (const float*)d_in[i];
        else if (sz == (long long)N_ * N_)         adj = (const int*)d_in[i];
        else if (sz == (long long)H_ * IN_ * OUT_) W   = (const float*)d_in[i];
        else if (sz == (long long)H_ * OUT_) {
            if (!a1) a1 = (const float*)d_in[i];
            else     a2 = (const float*)d_in[i];
        }
    }
    if (!x)   x   = (const float*)d_in[0];
    if (!adj) adj = (const int*)d_in[1];
    if (!W)   W   = (const float*)d_in[2];
    if (!a1)  a1  = (const float*)d_in[3];
    if (!a2)  a2  = (const float*)d_in[4];
    float* out = (float*)d_out;

    char* ws = (char*)d_ws;
    unsigned long long* bitsT = (unsigned long long*)ws;                     // 2 MB @0
    uint16_t* WhhT = (uint16_t*)(ws + (2u << 20));                           // 4 MB
    float* f1      = (float*)   (ws + (6u << 20));                           // 128 KB
    float* f2      = (float*)   (ws + (6u << 20) + (128u << 10));            // 128 KB
    uint16_t* WTh  = (uint16_t*)(ws + (6u << 20) + (512u << 10));            // 512 KB
    uint16_t* WTl  = (uint16_t*)(ws + (7u << 20));                           // 512 KB
    float2* EF1    = (float2*)  (ws + (7u << 20) + (512u << 10));            // 256 KB
    float2* EF2    = (float2*)  (ws + (7u << 20) + (768u << 10));            // 256 KB
    float* Lpart   = (float*)   (ws + (8u << 20));                           // 256 KB
    float* op1     = (float*)   (ws + (8u << 20) + (256u << 10));            // 8 MB

    pack_adj<<<(N_ * (size_t)N_) / 256, 256, 0, stream>>>(adj, bitsT);
    split_wT<<<dim3(IN_ / 64, H_), 256, 0, stream>>>(W, WTh, WTl);
    hipMemsetAsync(ws + (6u << 20), 0, 256u << 10, stream);                  // zero f1,f2
    wh_col<<<dim3(N_ / 64, H_, 4), 256, 0, stream>>>(x, WTh, WTl, a1, a2, WhhT, f1, f2);
    prep_ef<<<(H_ * N_) / 256, 256, 0, stream>>>(f1, f2, EF1, EF2);
    gat_main<<<dim3(N_ / 64, H_, 2), 256, 0, stream>>>(bitsT, WhhT, EF1, EF2, out, op1, Lpart);
    combine<<<(N_ * H_ * OUT_) / (256 * 4), 256, 0, stream>>>(out, op1, Lpart);
}

// Round 10
// 226.615 us; speedup vs baseline: 1.2816x; 1.0550x over previous
//
#include <hip/hip_runtime.h>
#include <hip/hip_bf16.h>
#include <stdint.h>

// N=4096, IN=512, OUT=64, H=8. Inputs (fp32): x, adj(int32), W, a1, a2. Output fp32[N, H*OUT].
// ws: bitsT 2M@0 | WhhT 4M@2M | WTh 512K@6M | WTl 512K@6.5M | EF1 256K@7M | EF2 256K@7.25M |
//     Lpart 512K@7.5M | opart (zc-1)*8M@8M   (zc=4 iff ws_size>=32M, else 2)

constexpr int N_ = 4096, IN_ = 512, OUT_ = 64, H_ = 8;
constexpr float ALPHA_ = 0.2f;

typedef __attribute__((ext_vector_type(8))) short short8;
typedef __attribute__((ext_vector_type(4))) float f32x4;

__device__ __forceinline__ uint32_t pkbf(float a, float b) {
    union { __hip_bfloat162 h2; uint32_t u; } c;
    c.h2 = __float22bfloat162_rn(make_float2(a, b));
    return c.u;
}
__device__ __forceinline__ uint32_t rne_pack2(float a, float b, float& ra, float& rb) {
    uint32_t ua = __float_as_uint(a); ua += 0x7fffu + ((ua >> 16) & 1u); ua >>= 16;
    uint32_t ub = __float_as_uint(b); ub += 0x7fffu + ((ub >> 16) & 1u); ub >>= 16;
    ra = __uint_as_float(ua << 16);
    rb = __uint_as_float(ub << 16);
    return ua | (ub << 16);
}
__device__ __forceinline__ short8 ld_bf8(const uint16_t* ptr) {
    union { uint4 v; short8 s; } u;
    u.v = *(const uint4*)ptr;
    return u.s;
}

// ---------- pack adj -> transposed bitmask bitsT[c*N + n], bit i = adj[n][c*64+i]
__global__ __launch_bounds__(256) void pack_adj(const int* __restrict__ adj,
                                                unsigned long long* __restrict__ bitsT) {
    size_t g = (size_t)blockIdx.x * 256 + threadIdx.x;   // g = n*4096 + m
    int v = adj[g];
    unsigned long long m = __ballot(v != 0);
    if ((threadIdx.x & 63) == 0) {
        int n = (int)(g >> 12);
        int c = (int)((g >> 6) & 63);
        bitsT[(size_t)c * N_ + n] = m;
    }
}

// ---------- W [h][k][o] fp32 -> WT hi/lo bf16 [h][o][k] (B-operand layout)
__global__ __launch_bounds__(256) void split_wT(const float* __restrict__ W,
                                                uint16_t* __restrict__ WTh,
                                                uint16_t* __restrict__ WTl) {
    __shared__ float T[64 * 68];
    const int t  = threadIdx.x;
    const int kb = blockIdx.x;   // 0..7
    const int h  = blockIdx.y;
    {
        int kk = t >> 2, os = (t & 3) * 16;
        const float* src = W + ((size_t)h * IN_ + kb * 64 + kk) * OUT_ + os;
#pragma unroll
        for (int j = 0; j < 4; j++)
            *(float4*)&T[kk * 68 + os + j * 4] = *(const float4*)(src + j * 4);
    }
    __syncthreads();
    int o = t >> 2, ks = (t & 3) * 16;
    uint32_t ph[8], pl[8];
#pragma unroll
    for (int i = 0; i < 8; i++) {
        float va = T[(ks + 2 * i) * 68 + o], vb = T[(ks + 2 * i + 1) * 68 + o];
        float h0, h1, d0, d1;
        ph[i] = rne_pack2(va, vb, h0, h1);
        pl[i] = rne_pack2(va - h0, vb - h1, d0, d1);
    }
    size_t dst = ((size_t)h * OUT_ + o) * IN_ + kb * 64 + ks;
    *(uint4*)&WTh[dst]     = make_uint4(ph[0], ph[1], ph[2], ph[3]);
    *(uint4*)&WTh[dst + 8] = make_uint4(ph[4], ph[5], ph[6], ph[7]);
    *(uint4*)&WTl[dst]     = make_uint4(pl[0], pl[1], pl[2], pl[3]);
    *(uint4*)&WTl[dst + 8] = make_uint4(pl[4], pl[5], pl[6], pl[7]);
}

// ---------- Wh GEMM: grid (128,8), block = 32 rows x 64 cols. Wave w: rows (w&1)*16,
// cols (w>>1)*32 (2 MFMA col-tiles). Hi/lo 3-MFMA (fp32-accurate).
// Fused epilogue: EF1/EF2 (factored-exp vectors) + WhhT bf16 [h][o][n].
__global__ __launch_bounds__(256) void wh_all(const float* __restrict__ x,
                                              const uint16_t* __restrict__ WTh,
                                              const uint16_t* __restrict__ WTl,
                                              const float* __restrict__ a1,
                                              const float* __restrict__ a2,
                                              uint16_t* __restrict__ WhhT,
                                              float2* __restrict__ EF1,
                                              float2* __restrict__ EF2) {
    __shared__ float Ws[32 * 68];
    const int t = threadIdx.x, h = blockIdx.y, n0 = blockIdx.x * 32;
    const int l = t & 63, w = t >> 6, p = l & 15, q = l >> 4;
    const int r0 = (w & 1) * 16;
    const int c0 = (w >> 1) * 32;

    f32x4 acc0 = (f32x4){0.f, 0.f, 0.f, 0.f};
    f32x4 acc1 = (f32x4){0.f, 0.f, 0.f, 0.f};
    const float* gx = x + (size_t)(n0 + r0 + p) * IN_ + q * 8;
    const uint16_t* gbh0 = WTh + ((size_t)h * OUT_ + c0 + p) * IN_ + q * 8;
    const uint16_t* gbl0 = WTl + ((size_t)h * OUT_ + c0 + p) * IN_ + q * 8;
    const uint16_t* gbh1 = gbh0 + (size_t)16 * IN_;
    const uint16_t* gbl1 = gbl0 + (size_t)16 * IN_;

#pragma unroll 4
    for (int ks = 0; ks < 16; ks++) {
        const int off = ks * 32;
        float4 xa = *(const float4*)(gx + off);
        float4 xb = *(const float4*)(gx + off + 4);
        float va[8] = {xa.x, xa.y, xa.z, xa.w, xb.x, xb.y, xb.z, xb.w};
        union { short8 s; uint32_t u[4]; } ah, al;
#pragma unroll
        for (int i = 0; i < 4; i++) {
            ah.u[i] = pkbf(va[2 * i], va[2 * i + 1]);
            float ha = __uint_as_float(ah.u[i] << 16);
            float hb = __uint_as_float(ah.u[i] & 0xffff0000u);
            al.u[i] = pkbf(va[2 * i] - ha, va[2 * i + 1] - hb);
        }
        short8 bh0 = ld_bf8(gbh0 + off), bl0 = ld_bf8(gbl0 + off);
        short8 bh1 = ld_bf8(gbh1 + off), bl1 = ld_bf8(gbl1 + off);
        acc0 = __builtin_amdgcn_mfma_f32_16x16x32_bf16(ah.s, bh0, acc0, 0, 0, 0);
        acc0 = __builtin_amdgcn_mfma_f32_16x16x32_bf16(al.s, bh0, acc0, 0, 0, 0);
        acc0 = __builtin_amdgcn_mfma_f32_16x16x32_bf16(ah.s, bl0, acc0, 0, 0, 0);
        acc1 = __builtin_amdgcn_mfma_f32_16x16x32_bf16(ah.s, bh1, acc1, 0, 0, 0);
        acc1 = __builtin_amdgcn_mfma_f32_16x16x32_bf16(al.s, bh1, acc1, 0, 0, 0);
        acc1 = __builtin_amdgcn_mfma_f32_16x16x32_bf16(ah.s, bl1, acc1, 0, 0, 0);
    }
    // D[m][o]: m = q*4+reg (row r0+m), o-col = p
#pragma unroll
    for (int reg = 0; reg < 4; reg++) {
        Ws[(r0 + q * 4 + reg) * 68 + c0 + p]      = acc0[reg];
        Ws[(r0 + q * 4 + reg) * 68 + c0 + 16 + p] = acc1[reg];
    }
    __syncthreads();
    if (t < 128) {   // f1/f2 dots -> EF vectors. 4 threads per row.
        int r = t >> 2, og = (t & 3) * 16;
        float s1 = 0.f, s2 = 0.f;
#pragma unroll
        for (int j = 0; j < 4; j++) {
            float4 wv = *(const float4*)&Ws[r * 68 + og + j * 4];
            float4 av = *(const float4*)(a1 + h * OUT_ + og + j * 4);
            float4 bv = *(const float4*)(a2 + h * OUT_ + og + j * 4);
            s1 += wv.x * av.x + wv.y * av.y + wv.z * av.z + wv.w * av.w;
            s2 += wv.x * bv.x + wv.y * bv.y + wv.z * bv.z + wv.w * bv.w;
        }
        s1 += __shfl_xor(s1, 1, 64); s1 += __shfl_xor(s1, 2, 64);
        s2 += __shfl_xor(s2, 1, 64); s2 += __shfl_xor(s2, 2, 64);
        if ((t & 3) == 0) {
            EF1[(size_t)h * N_ + n0 + r] = make_float2(__expf(s1), __expf(ALPHA_ * s1));
            EF2[(size_t)h * N_ + n0 + r] = make_float2(__expf(s2), __expf(ALPHA_ * s2));
        }
    }
    {   // WhhT bf16 [h][o][n]: 64 o x 32 n, thread = (o, 8n)
        int o = t >> 2, ns = (t & 3) * 8;
        uint32_t ph[4];
#pragma unroll
        for (int i = 0; i < 4; i++)
            ph[i] = pkbf(Ws[(ns + 2 * i) * 68 + o], Ws[(ns + 2 * i + 1) * 68 + o]);
        *(uint4*)&WhhT[((size_t)h * OUT_ + o) * N_ + n0 + ns] = make_uint4(ph[0], ph[1], ph[2], ph[3]);
    }
}

// ---------- main: double-buffered LDS B-tile, 1 barrier/chunk, Bh+word reg-prefetch.
// grid (64, 8, zc): raw numerators (z=0 -> out, else opart) + L partials.
__global__ __launch_bounds__(256) void gat_main(const unsigned long long* __restrict__ bitsT,
                                                const uint16_t* __restrict__ WhhT,
                                                const float2* __restrict__ EF1,
                                                const float2* __restrict__ EF2,
                                                float* __restrict__ out,
                                                float* __restrict__ opart,
                                                float* __restrict__ Lpart) {
    __shared__ __align__(16) uint16_t Bh[2][64 * 72];   // 18432 B
    const int t = threadIdx.x, h = blockIdx.y, z = blockIdx.z, n0 = blockIdx.x * 64;
    const int nch = 64 / gridDim.z, cbase = z * nch;
    const int l = t & 63, w = t >> 6, p = l & 15, q = l >> 4;
    const int sr = t >> 2, sc = (t & 3) * 16;
    const int row = w * 16 + p;

    const float2 ef1 = EF1[(size_t)h * N_ + n0 + row];
    const float E1v = ef1.x, F1v = ef1.y;
    const float2* efb = EF2 + (size_t)h * N_ + q * 8;
    const unsigned long long* bp = bitsT + n0 + row;
    const uint16_t* gb = WhhT + ((size_t)h * OUT_ + sr) * N_ + sc;

    short8 ones;
    {
        union { short8 s; uint32_t u[4]; } o;
        o.u[0] = o.u[1] = o.u[2] = o.u[3] = 0x3f803f80u;
        ones = o.s;
    }

    f32x4 acc[4], accL;
#pragma unroll
    for (int ct = 0; ct < 4; ct++) acc[ct] = (f32x4){0.f, 0.f, 0.f, 0.f};
    accL = (f32x4){0.f, 0.f, 0.f, 0.f};

    // prologue: chunk cbase -> regs -> LDS[0]
    uint4 pb0 = *(const uint4*)(gb + cbase * 64);
    uint4 pb1 = *(const uint4*)(gb + cbase * 64 + 8);
    unsigned long long word = bp[(size_t)cbase * N_];
    *(uint4*)&Bh[0][sr * 72 + sc]     = pb0;
    *(uint4*)&Bh[0][sr * 72 + sc + 8] = pb1;

    for (int cc = 0; cc < nch; cc++) {
        const int cur = cc & 1;
        const int m0 = (cbase + cc) * 64;
        uint4 nb0, nb1;
        unsigned long long nword = 0;
        if (cc + 1 < nch) {   // issue next-chunk loads; they fly during the barrier
            nb0 = *(const uint4*)(gb + m0 + 64);
            nb1 = *(const uint4*)(gb + m0 + 64 + 8);
            nword = bp[(size_t)(cbase + cc + 1) * N_];
        }
        __syncthreads();      // LDS[cur] writes visible; prior reads of LDS[cur^1] done
        // P fragments (factored exp), both k0 halves
        union { short8 s; uint32_t u[4]; } af[2];
#pragma unroll
        for (int k0 = 0; k0 < 2; k0++) {
            const float4* ep = (const float4*)(efb + m0 + k0 * 32);
            float4 e0 = ep[0], e1 = ep[1], e2 = ep[2], e3 = ep[3];
            float ev[8] = {e0.x, e0.z, e1.x, e1.z, e2.x, e2.z, e3.x, e3.z};
            float fv[8] = {e0.y, e0.w, e1.y, e1.w, e2.y, e2.w, e3.y, e3.w};
            uint32_t bits8 = (uint32_t)(word >> (k0 * 32 + q * 8)) & 0xffu;
            float pv[8];
#pragma unroll
            for (int j = 0; j < 8; j++) {
                float m = fmaxf(E1v * ev[j], F1v * fv[j]);
                pv[j] = ((bits8 >> j) & 1u) ? m : 0.f;
            }
#pragma unroll
            for (int i = 0; i < 4; i++) af[k0].u[i] = pkbf(pv[2 * i], pv[2 * i + 1]);
        }
#pragma unroll
        for (int k0 = 0; k0 < 2; k0++) {
            short8 bb0 = ld_bf8(&Bh[cur][(0 * 16 + p) * 72 + q * 8 + k0 * 32]);
            short8 bb1 = ld_bf8(&Bh[cur][(1 * 16 + p) * 72 + q * 8 + k0 * 32]);
            short8 bb2 = ld_bf8(&Bh[cur][(2 * 16 + p) * 72 + q * 8 + k0 * 32]);
            short8 bb3 = ld_bf8(&Bh[cur][(3 * 16 + p) * 72 + q * 8 + k0 * 32]);
            accL   = __builtin_amdgcn_mfma_f32_16x16x32_bf16(af[k0].s, ones, accL, 0, 0, 0);
            acc[0] = __builtin_amdgcn_mfma_f32_16x16x32_bf16(af[k0].s, bb0, acc[0], 0, 0, 0);
            acc[1] = __builtin_amdgcn_mfma_f32_16x16x32_bf16(af[k0].s, bb1, acc[1], 0, 0, 0);
            acc[2] = __builtin_amdgcn_mfma_f32_16x16x32_bf16(af[k0].s, bb2, acc[2], 0, 0, 0);
            acc[3] = __builtin_amdgcn_mfma_f32_16x16x32_bf16(af[k0].s, bb3, acc[3], 0, 0, 0);
        }
        if (cc + 1 < nch) {   // fill the other buffer (safe: barrier gated prior reads)
            *(uint4*)&Bh[cur ^ 1][sr * 72 + sc]     = nb0;
            *(uint4*)&Bh[cur ^ 1][sr * 72 + sc + 8] = nb1;
            word = nword;
        }
    }
    if (p == 0) {
#pragma unroll
        for (int reg = 0; reg < 4; reg++)
            Lpart[((size_t)z * 8 + h) * N_ + n0 + w * 16 + q * 4 + reg] = accL[reg];
    }
    float* dst = (z == 0) ? out : (opart + (size_t)(z - 1) * N_ * H_ * OUT_);
#pragma unroll
    for (int ct = 0; ct < 4; ct++)
#pragma unroll
        for (int reg = 0; reg < 4; reg++) {
            int rr = w * 16 + q * 4 + reg;
            dst[(size_t)(n0 + rr) * (H_ * OUT_) + h * OUT_ + ct * 16 + p] = acc[ct][reg];
        }
}

// ---------- combine z partials + normalize
__global__ __launch_bounds__(256) void combine(float* __restrict__ outb,
                                               const float* __restrict__ opart,
                                               const float* __restrict__ Lpart,
                                               int zc) {
    size_t g = (size_t)blockIdx.x * 256 + threadIdx.x;   // float4 index
    int n = (int)(g >> 7);
    int c = (int)(g & 127);
    int h = c >> 4;
    float4 o = ((const float4*)outb)[g];
    for (int zz = 1; zz < zc; zz++) {
        float4 o1 = ((const float4*)(opart + (size_t)(zz - 1) * N_ * H_ * OUT_))[g];
        o.x += o1.x; o.y += o1.y; o.z += o1.z; o.w += o1.w;
    }
    float L = 0.f;
    for (int zz = 0; zz < zc; zz++) L += Lpart[((size_t)zz * 8 + h) * N_ + n];
    float inv = 1.f / L;
    ((float4*)outb)[g] = make_float4(o.x * inv, o.y * inv, o.z * inv, o.w * inv);
}

extern "C" void kernel_launch(void* const* d_in, const int* in_sizes, int n_in,
                              void* d_out, int out_size, void* d_ws, size_t ws_size,
                              hipStream_t stream) {
    const float* x   = nullptr;
    const int*   adj = nullptr;
    const float* W   = nullptr;
    const float* a1  = nullptr;
    const float* a2  = nullptr;
    for (int i = 0; i < n_in; i++) {
        long long sz = in_sizes[i];
        if      (sz == (long long)N_ * IN_)        x   = (const float*)d_in[i];
        else if (sz == (long long)N_ * N_)         adj = (const int*)d_in[i];
        else if (sz == (long long)H_ * IN_ * OUT_) W   = (const float*)d_in[i];
        else if (sz == (long long)H_ * OUT_) {
            if (!a1) a1 = (const float*)d_in[i];
            else     a2 = (const float*)d_in[i];
        }
    }
    if (!x)   x   = (const float*)d_in[0];
    if (!adj) adj = (const int*)d_in[1];
    if (!W)   W   = (const float*)d_in[2];
    if (!a1)  a1  = (const float*)d_in[3];
    if (!a2)  a2  = (const float*)d_in[4];
    float* out = (float*)d_out;

    char* ws = (char*)d_ws;
    unsigned long long* bitsT = (unsigned long long*)ws;                 // 2 MB @0
    uint16_t* WhhT = (uint16_t*)(ws + (2u << 20));                       // 4 MB
    uint16_t* WTh  = (uint16_t*)(ws + (6u << 20));                       // 512 KB
    uint16_t* WTl  = (uint16_t*)(ws + (6u << 20) + (512u << 10));        // 512 KB
    float2* EF1    = (float2*)  (ws + (7u << 20));                       // 256 KB
    float2* EF2    = (float2*)  (ws + (7u << 20) + (256u << 10));        // 256 KB
    float* Lpart   = (float*)   (ws + (7u << 20) + (512u << 10));        // 512 KB
    float* opart   = (float*)   (ws + (8u << 20));                       // (zc-1)*8 MB

    const int zc = (ws_size >= (32ull << 20)) ? 4 : 2;

    pack_adj<<<(N_ * (size_t)N_) / 256, 256, 0, stream>>>(adj, bitsT);
    split_wT<<<dim3(IN_ / 64, H_), 256, 0, stream>>>(W, WTh, WTl);
    wh_all<<<dim3(N_ / 32, H_), 256, 0, stream>>>(x, WTh, WTl, a1, a2, WhhT, EF1, EF2);
    gat_main<<<dim3(N_ / 64, H_, zc), 256, 0, stream>>>(bitsT, WhhT, EF1, EF2, out, opart, Lpart);
    combine<<<(N_ * H_ * OUT_) / (256 * 4), 256, 0, stream>>>(out, opart, Lpart, zc);
}